// Round 2
// baseline (151.760 us; speedup 1.0000x reference)
//
#include <hip/hip_runtime.h>

// ContextVector additive-attention (Bahdanau) fused kernel set — round 2.
// Shapes (fixed):
//   encoder_outputs: (8, 512, 256) f32
//   decoder_states:  (8, 256, 512) f32
//   W_enc: (256,256)  W_dec: (512,256)  v: (256,1)
// Outputs: context (8,256,256) then weights (8,256,512), f32, concat in d_out.
//
// R2 change vs R1: attn_kernel 256 -> 1024 threads/block (16 waves), same 512
// blocks => 32 waves/CU (was 8). Phases repartitioned so total FLOPs are
// unchanged (no redundant decW work). K2/LOG2E constants folded upstream.

constexpr int B  = 8;
constexpr int TE = 512;   // T_enc
constexpr int DE = 256;   // D_enc
constexpr int TD = 256;   // T_dec
constexpr int DD = 512;   // D_dec

constexpr float LOG2E = 1.4426950408889634f;
constexpr float K2    = 2.8853900817779268f;   // 2*log2(e): exp2(K2*z) == exp(2z)

__device__ __forceinline__ float fexp2(float x){ return __builtin_amdgcn_exp2f(x); }
__device__ __forceinline__ float frcp (float x){ return __builtin_amdgcn_rcpf(x); }

// Kernel A: encWT[b][e][t] = K2 * sum_k enc[b][t][k] * Wenc[k][e]  (transposed)
// grid 512 x 256 threads; thread owns one row (b,t) and 8 e-columns via LDS.
__global__ __launch_bounds__(256)
void encw_kernel(const float* __restrict__ enc, const float* __restrict__ Wenc,
                 float* __restrict__ encWT)
{
  __shared__ __align__(16) float Ws[8*256];   // Ws[i][k] = Wenc[k][e0+i]
  const int tid = threadIdx.x;
  const int rg = blockIdx.x >> 5;   // 16 row groups of 256 rows
  const int eg = blockIdx.x & 31;   // 32 e-groups of 8 cols
  const int e0 = eg*8;
  {
    const float* wsrc = Wenc + tid*DE + e0;   // thread tid stages k=tid
    #pragma unroll
    for (int i=0;i<8;i++) Ws[i*256 + tid] = wsrc[i];
  }
  __syncthreads();
  const int row = rg*256 + tid;     // [0,4096)
  const int b = row >> 9;
  const int t = row & (TE-1);
  const float* rp = enc + (size_t)row*DE;
  float acc[8];
  #pragma unroll
  for (int i=0;i<8;i++) acc[i]=0.f;
  #pragma unroll 4
  for (int k4=0;k4<DE/4;k4++){
    const float4 a = *(const float4*)(rp + 4*k4);
    #pragma unroll
    for (int i=0;i<8;i++){
      const float4 w = *(const float4*)(&Ws[i*256 + 4*k4]);   // LDS broadcast
      acc[i] += a.x*w.x + a.y*w.y + a.z*w.z + a.w*w.w;
    }
  }
  float* op = encWT + (size_t)(b*DE + e0)*TE + t;   // coalesced (t contiguous)
  #pragma unroll
  for (int i=0;i<8;i++) op[i*TE] = K2*acc[i];
}

// Main kernel: one block per (b, 4 decoder steps). 512 blocks x 1024 threads.
// phase0: dw[s][e] = K2 * (dec[b,s0+s,:] @ Wdec[:,e])      thread=(s,e)
// phase1: pl[s][t] = -K2*sum_e v[e]*rcp(1+exp2(encWT+dw))  thread=(s,t-pair)
//         (alpha*LOG2E up to an additive const; softmax is shift-invariant)
// phase2: softmax over t: 4 waves per s, two-level reduce; writes weights
// phase3: context[s][e] = (sum_t exp[s][t]*enc[b][t][e]) * rs[s]  thread=(s,e)
__global__ __launch_bounds__(1024, 8)
void attn_kernel(const float* __restrict__ enc, const float* __restrict__ dec,
                 const float* __restrict__ Wdec, const float* __restrict__ v,
                 const float* __restrict__ encWT,
                 float* __restrict__ outCtx, float* __restrict__ outW)
{
  __shared__ __align__(16) float Ds[4*DD];     // 8 KB: 4 dec rows
  __shared__ __align__(16) float dw[4][DE];    // 4 KB
  __shared__ float vv[DE];                     // 1 KB
  __shared__ __align__(16) float pl[4][TE];    // 8 KB: log2-logits -> exp vals
  __shared__ float pmax[16], psum[16], rs[4];
  const int tid = threadIdx.x;
  const int b  = blockIdx.x >> 6;
  const int s0 = (blockIdx.x & 63)*4;

  {
    const float* src = dec + (size_t)(b*TD + s0)*DD;   // 4 contiguous rows
    Ds[tid] = src[tid];
    Ds[tid + 1024] = src[tid + 1024];
    if (tid < DE) vv[tid] = v[tid];
  }
  __syncthreads();

  const int s = tid >> 8;     // 0..3
  const int q = tid & 255;    // e (p0,p3) or t-pair (p1)

  // ---- phase 0: decoder projection, thread = (s, e=q), 512 MACs each ----
  {
    float a = 0.f;
    const float* wp  = Wdec + q;          // column e=q, stride DE; lanes coalesced
    const float* dsp = Ds + s*DD;         // wave-uniform row s -> LDS broadcast
    #pragma unroll 4
    for (int k4=0;k4<DD/4;k4++){
      const float4 qd = *(const float4*)(dsp + 4*k4);
      a += qd.x*wp[(size_t)(4*k4  )*DE] + qd.y*wp[(size_t)(4*k4+1)*DE]
         + qd.z*wp[(size_t)(4*k4+2)*DE] + qd.w*wp[(size_t)(4*k4+3)*DE];
    }
    dw[s][q] = a*K2;
  }
  __syncthreads();

  // ---- phase 1: energies, thread = (s, t in {2q, 2q+1}) ----
  {
    float a0=0.f, a1=0.f;
    const float* ep  = encWT + (size_t)(b*DE)*TE + 2*q;   // coalesced b64
    const float* dws = dw[s];                              // uniform broadcasts
    #pragma unroll 4
    for (int e=0;e<DE;e++){
      const float2 x = *(const float2*)(ep + (size_t)e*TE);
      const float d  = dws[e];
      const float ve = vv[e];
      a0 += ve*frcp(1.f + fexp2(x.x + d));
      a1 += ve*frcp(1.f + fexp2(x.y + d));
    }
    float2 st; st.x = -K2*a0; st.y = -K2*a1;   // log2-domain logits (+ const)
    *(float2*)&pl[s][2*q] = st;
  }
  __syncthreads();

  // ---- phase 2: softmax, wave w = (s=w>>2, chunk c=w&3) over 128 t each ----
  {
    const int w = tid>>6, lane = tid&63;
    const int ss = w>>2, c = w&3;
    float2 x = *(const float2*)&pl[ss][c*128 + 2*lane];
    float m = fmaxf(x.x, x.y);
    #pragma unroll
    for (int off=32; off>=1; off>>=1) m = fmaxf(m, __shfl_xor(m, off));
    if (lane==0) pmax[w] = m;
    __syncthreads();
    const float M = fmaxf(fmaxf(pmax[ss*4],pmax[ss*4+1]),
                          fmaxf(pmax[ss*4+2],pmax[ss*4+3]));
    const float e0 = fexp2(x.x - M), e1 = fexp2(x.y - M);
    float2 ee; ee.x = e0; ee.y = e1;
    *(float2*)&pl[ss][c*128 + 2*lane] = ee;   // own slot: race-free
    float sum = e0 + e1;
    #pragma unroll
    for (int off=32; off>=1; off>>=1) sum += __shfl_xor(sum, off);
    if (lane==0) psum[w] = sum;
    __syncthreads();
    const float S = psum[ss*4]+psum[ss*4+1]+psum[ss*4+2]+psum[ss*4+3];
    const float r = 1.0f / S;
    float2 wo; wo.x = e0*r; wo.y = e1*r;
    *(float2*)(outW + (size_t)(b*TD + s0 + ss)*TE + c*128 + 2*lane) = wo;
    if (c==0 && lane==0) rs[ss] = r;
  }
  __syncthreads();

  // ---- phase 3: context, thread = (s, e=q), 512 MACs each ----
  {
    float c0 = 0.f;
    const float* encB = enc + (size_t)b*TE*DE + q;  // lanes e-consecutive
    const float* ps   = pl[s];                       // uniform b128 broadcast
    #pragma unroll 2
    for (int t4=0;t4<TE/4;t4++){
      const float4 p = *(const float4*)(ps + 4*t4);
      c0 += p.x*encB[(size_t)(4*t4  )*DE] + p.y*encB[(size_t)(4*t4+1)*DE]
          + p.z*encB[(size_t)(4*t4+2)*DE] + p.w*encB[(size_t)(4*t4+3)*DE];
    }
    outCtx[(size_t)(b*TD + s0 + s)*DE + q] = c0*rs[s];
  }
}

extern "C" void kernel_launch(void* const* d_in, const int* in_sizes, int n_in,
                              void* d_out, int out_size, void* d_ws, size_t ws_size,
                              hipStream_t stream)
{
  const float* enc  = (const float*)d_in[0];
  const float* dec  = (const float*)d_in[1];
  const float* Wenc = (const float*)d_in[2];
  const float* Wdec = (const float*)d_in[3];
  const float* v    = (const float*)d_in[4];
  float* outCtx = (float*)d_out;                       // (8,256,256)
  float* outW   = outCtx + (size_t)B*TD*DE;            // (8,256,512)
  float* encWT  = (float*)d_ws;                        // 4 MB scratch

  hipLaunchKernelGGL(encw_kernel, dim3(512), dim3(256), 0, stream,
                     enc, Wenc, encWT);
  hipLaunchKernelGGL(attn_kernel, dim3(512), dim3(1024), 0, stream,
                     enc, dec, Wdec, v, encWT, outCtx, outW);
}

// Round 3
// 130.431 us; speedup vs baseline: 1.1635x; 1.1635x over previous
//
#include <hip/hip_runtime.h>

// ContextVector additive-attention (Bahdanau) — round 3.
// Shapes: enc (8,512,256) f32, dec (8,256,512) f32, W_enc (256,256),
//         W_dec (512,256), v (256,1). Out: context (8,256,256) ++ weights (8,256,512).
//
// R3 vs R2: restore 4-way s reuse (block = (b, 4 s)) while keeping 16 waves/CU
// via e/t/k-split reductions inside a 512-thread block. decW hoisted into its
// own GEMM kernel (2 MB table) so attn blocks don't all re-read Wdec. Phase-1
// inner loop: float4 loads, 16 independent trans chains, ~310 issue-cyc per
// global load -> latency-proof.

constexpr int B  = 8;
constexpr int TE = 512;   // T_enc
constexpr int DE = 256;   // D_enc
constexpr int TD = 256;   // T_dec
constexpr int DD = 512;   // D_dec

constexpr float K2 = 2.8853900817779268f;   // 2*log2(e): exp2(K2*z) == exp(2z)

__device__ __forceinline__ float fexp2(float x){ return __builtin_amdgcn_exp2f(x); }
__device__ __forceinline__ float frcp (float x){ return __builtin_amdgcn_rcpf(x); }

// encWT[b][e][t] = K2 * sum_k enc[b][t][k] * Wenc[k][e]   (transposed store)
__global__ __launch_bounds__(256)
void encw_kernel(const float* __restrict__ enc, const float* __restrict__ Wenc,
                 float* __restrict__ encWT)
{
  __shared__ __align__(16) float Ws[8*256];   // Ws[i][k] = Wenc[k][e0+i]
  const int tid = threadIdx.x;
  const int rg = blockIdx.x >> 5;
  const int eg = blockIdx.x & 31;
  const int e0 = eg*8;
  {
    const float* wsrc = Wenc + tid*DE + e0;
    #pragma unroll
    for (int i=0;i<8;i++) Ws[i*256 + tid] = wsrc[i];
  }
  __syncthreads();
  const int row = rg*256 + tid;     // row = b*TE + t
  const int b = row >> 9;
  const int t = row & (TE-1);
  const float* rp = enc + (size_t)row*DE;
  float acc[8];
  #pragma unroll
  for (int i=0;i<8;i++) acc[i]=0.f;
  #pragma unroll 4
  for (int k4=0;k4<DE/4;k4++){
    const float4 a = *(const float4*)(rp + 4*k4);
    #pragma unroll
    for (int i=0;i<8;i++){
      const float4 w = *(const float4*)(&Ws[i*256 + 4*k4]);
      acc[i] += a.x*w.x + a.y*w.y + a.z*w.z + a.w*w.w;
    }
  }
  float* op = encWT + (size_t)(b*DE + e0)*TE + t;
  #pragma unroll
  for (int i=0;i<8;i++) op[i*TE] = K2*acc[i];
}

// decWT[b*TD+s][e] = K2 * sum_k dec[b][s][k] * Wdec[k][e]   (row-major)
__global__ __launch_bounds__(256)
void decw_kernel(const float* __restrict__ dec, const float* __restrict__ Wdec,
                 float* __restrict__ decWT)
{
  __shared__ __align__(16) float Ws[8*512];   // 16 KB: Ws[i][k] = Wdec[k][e0+i]
  const int tid = threadIdx.x;
  const int rg = blockIdx.x >> 5;   // 8 row-groups of 256 rows (2048 total)
  const int eg = blockIdx.x & 31;
  const int e0 = eg*8;
  #pragma unroll
  for (int kk=0; kk<2; kk++){
    const int k = kk*256 + tid;
    const float* wsrc = Wdec + (size_t)k*DE + e0;
    const float4 wa = *(const float4*)wsrc;
    const float4 wb = *(const float4*)(wsrc+4);
    Ws[0*512+k]=wa.x; Ws[1*512+k]=wa.y; Ws[2*512+k]=wa.z; Ws[3*512+k]=wa.w;
    Ws[4*512+k]=wb.x; Ws[5*512+k]=wb.y; Ws[6*512+k]=wb.z; Ws[7*512+k]=wb.w;
  }
  __syncthreads();
  const int row = rg*256 + tid;     // row = b*TD + s
  const float* rp = dec + (size_t)row*DD;
  float acc[8];
  #pragma unroll
  for (int i=0;i<8;i++) acc[i]=0.f;
  #pragma unroll 2
  for (int k4=0;k4<DD/4;k4++){
    const float4 a = *(const float4*)(rp + 4*k4);
    #pragma unroll
    for (int i=0;i<8;i++){
      const float4 w = *(const float4*)(&Ws[i*512 + 4*k4]);
      acc[i] += a.x*w.x + a.y*w.y + a.z*w.z + a.w*w.w;
    }
  }
  float* op = decWT + (size_t)row*DE + e0;
  #pragma unroll
  for (int i=0;i<8;i++) op[i] = K2*acc[i];
}

// Main kernel: block = (b, 4 decoder steps). 512 blocks x 512 threads.
template<bool USE_DWT>
__global__ __launch_bounds__(512, 4)
void attn_kernel(const float* __restrict__ enc, const float* __restrict__ dec,
                 const float* __restrict__ Wdec, const float* __restrict__ v,
                 const float* __restrict__ encWT, const float* __restrict__ decWT,
                 float* __restrict__ outCtx, float* __restrict__ outW)
{
  __shared__ __align__(16) float tw[DE][4];       // 4 KB {d_s0..d_s3} per e
  __shared__ float vv[DE];                        // 1 KB
  __shared__ __align__(16) float part[4][4][TE];  // 32 KB [g][s][t]; reused ph3
  __shared__ __align__(16) float pl[4][TE];       // 8 KB exp values
  __shared__ float wred[8], wsum2[8], rs[4];
  __shared__ __align__(16) float Ds[USE_DWT ? 4 : 4*DD];  // 8 KB if inline dw

  const int tid = threadIdx.x;
  const int b  = blockIdx.x >> 6;
  const int s0 = (blockIdx.x & 63)*4;

  if (USE_DWT){
    if (tid < DE){
      const float* dp = decWT + (size_t)(b*TD + s0)*DE + tid;  // 4 coalesced rows
      float4 t4; t4.x = dp[0]; t4.y = dp[DE]; t4.z = dp[2*DE]; t4.w = dp[3*DE];
      *(float4*)&tw[tid][0] = t4;
      vv[tid] = v[tid];
    }
    __syncthreads();
  } else {
    {
      const float* src = dec + (size_t)(b*TD + s0)*DD;   // 2048 floats
      float* dsf = (float*)Ds;
      #pragma unroll
      for (int i=0;i<4;i++) dsf[tid + i*512] = src[tid + i*512];
      if (tid < DE) vv[tid] = v[tid];
    }
    __syncthreads();
    // inline phase 0: thread (h, e) computes dw for s = s0+2h, s0+2h+1
    const int h = tid >> 8, e = tid & 255;
    float a0=0.f, a1=0.f;
    const float* wp  = Wdec + e;
    const float* d0p = (const float*)Ds + (2*h  )*DD;
    const float* d1p = (const float*)Ds + (2*h+1)*DD;
    #pragma unroll 2
    for (int k4=0;k4<DD/4;k4++){
      const float4 qa = *(const float4*)(d0p + 4*k4);
      const float4 qb = *(const float4*)(d1p + 4*k4);
      const float w0 = wp[(size_t)(4*k4  )*DE];
      const float w1 = wp[(size_t)(4*k4+1)*DE];
      const float w2 = wp[(size_t)(4*k4+2)*DE];
      const float w3 = wp[(size_t)(4*k4+3)*DE];
      a0 += qa.x*w0+qa.y*w1+qa.z*w2+qa.w*w3;
      a1 += qb.x*w0+qb.y*w1+qb.z*w2+qb.w*w3;
    }
    float2 o; o.x = a0*K2; o.y = a1*K2;
    *(float2*)&tw[e][2*h] = o;
    __syncthreads();
  }

  // ---- phase 1: energies. thread (g = e-quarter, q = t-quad). ----
  // acc[s] (float4 over 4 t) -> 16 independent trans chains per thread.
  {
    const int g = tid >> 7, q = tid & 127;
    float4 acc[4];
    #pragma unroll
    for (int s=0;s<4;s++){ acc[s].x=0;acc[s].y=0;acc[s].z=0;acc[s].w=0; }
    const float* xp = encWT + (size_t)(b*DE + 64*g)*TE + 4*q;
    #pragma unroll 2
    for (int i=0;i<64;i++){
      const float4 x = *(const float4*)(xp + (size_t)i*TE);
      const int e = 64*g + i;
      const float4 d = *(const float4*)&tw[e][0];   // uniform b128
      const float ve = vv[e];                       // uniform b32
      #pragma unroll
      for (int s=0;s<4;s++){
        const float ds = (s==0)?d.x:(s==1)?d.y:(s==2)?d.z:d.w;
        acc[s].x += ve*frcp(1.f + fexp2(x.x + ds));
        acc[s].y += ve*frcp(1.f + fexp2(x.y + ds));
        acc[s].z += ve*frcp(1.f + fexp2(x.z + ds));
        acc[s].w += ve*frcp(1.f + fexp2(x.w + ds));
      }
    }
    #pragma unroll
    for (int s=0;s<4;s++) *(float4*)&part[g][s][4*q] = acc[s];
  }
  __syncthreads();

  // ---- phase 2: reduce partials + softmax. wave w: s = w>>1, half c = w&1 ----
  {
    const int w = tid >> 6, lane = tid & 63;
    const int s = w >> 1, c = w & 1;
    const int t0 = c*256 + 4*lane;
    const float4 p0 = *(const float4*)&part[0][s][t0];
    const float4 p1 = *(const float4*)&part[1][s][t0];
    const float4 p2 = *(const float4*)&part[2][s][t0];
    const float4 p3 = *(const float4*)&part[3][s][t0];
    float4 al;
    al.x = -K2*(p0.x+p1.x+p2.x+p3.x);
    al.y = -K2*(p0.y+p1.y+p2.y+p3.y);
    al.z = -K2*(p0.z+p1.z+p2.z+p3.z);
    al.w = -K2*(p0.w+p1.w+p2.w+p3.w);
    float m = fmaxf(fmaxf(al.x,al.y), fmaxf(al.z,al.w));
    #pragma unroll
    for (int off=32; off>=1; off>>=1) m = fmaxf(m, __shfl_xor(m, off));
    if (lane==0) wred[w] = m;
    __syncthreads();
    const float M = fmaxf(wred[2*s], wred[2*s+1]);
    float4 ex;
    ex.x = fexp2(al.x - M); ex.y = fexp2(al.y - M);
    ex.z = fexp2(al.z - M); ex.w = fexp2(al.w - M);
    float sum = ex.x+ex.y+ex.z+ex.w;
    #pragma unroll
    for (int off=32; off>=1; off>>=1) sum += __shfl_xor(sum, off);
    if (lane==0) wsum2[w] = sum;
    __syncthreads();
    const float S = wsum2[2*s] + wsum2[2*s+1];
    const float r = 1.0f / S;
    float4 wo; wo.x=ex.x*r; wo.y=ex.y*r; wo.z=ex.z*r; wo.w=ex.w*r;
    *(float4*)(outW + (size_t)(b*TD + s0 + s)*TE + t0) = wo;
    *(float4*)&pl[s][t0] = ex;
    if (lane==0 && c==0) rs[s] = r;
  }
  __syncthreads();

  // ---- phase 3: context. thread (h = t-half, e). 64 t-quads each. ----
  {
    const int h = tid >> 8, e = tid & 255;
    float c0=0.f, c1=0.f, c2=0.f, c3=0.f;
    const float* encB = enc + (size_t)(b*TE + 256*h)*DE + e;
    const float* pb = &pl[0][256*h];
    #pragma unroll 2
    for (int t4=0;t4<64;t4++){
      const float4 q0 = *(const float4*)(pb + 0*TE + 4*t4);
      const float4 q1 = *(const float4*)(pb + 1*TE + 4*t4);
      const float4 q2 = *(const float4*)(pb + 2*TE + 4*t4);
      const float4 q3 = *(const float4*)(pb + 3*TE + 4*t4);
      const float f0 = encB[(size_t)(4*t4  )*DE];
      const float f1 = encB[(size_t)(4*t4+1)*DE];
      const float f2 = encB[(size_t)(4*t4+2)*DE];
      const float f3 = encB[(size_t)(4*t4+3)*DE];
      c0 += q0.x*f0+q0.y*f1+q0.z*f2+q0.w*f3;
      c1 += q1.x*f0+q1.y*f1+q1.z*f2+q1.w*f3;
      c2 += q2.x*f0+q2.y*f1+q2.z*f2+q2.w*f3;
      c3 += q3.x*f0+q3.y*f1+q3.z*f2+q3.w*f3;
    }
    float* partc = &part[0][0][0];   // reuse 32 KB scratch: [h][s][e]
    partc[(h*4+0)*DE + e] = c0;
    partc[(h*4+1)*DE + e] = c1;
    partc[(h*4+2)*DE + e] = c2;
    partc[(h*4+3)*DE + e] = c3;
  }
  __syncthreads();
  if (tid < DE){
    const float* partc = &part[0][0][0];
    #pragma unroll
    for (int s=0;s<4;s++){
      const float val = (partc[s*DE + tid] + partc[(4+s)*DE + tid]) * rs[s];
      outCtx[(size_t)(b*TD + s0 + s)*DE + tid] = val;
    }
  }
}

extern "C" void kernel_launch(void* const* d_in, const int* in_sizes, int n_in,
                              void* d_out, int out_size, void* d_ws, size_t ws_size,
                              hipStream_t stream)
{
  const float* enc  = (const float*)d_in[0];
  const float* dec  = (const float*)d_in[1];
  const float* Wenc = (const float*)d_in[2];
  const float* Wdec = (const float*)d_in[3];
  const float* v    = (const float*)d_in[4];
  float* outCtx = (float*)d_out;                       // (8,256,256)
  float* outW   = outCtx + (size_t)B*TD*DE;            // (8,256,512)
  float* encWT  = (float*)d_ws;                        // 4 MB
  float* decWT  = encWT + (size_t)B*DE*TE;             // 2 MB

  const bool use_dwt = ws_size >= (size_t)(B*DE*TE + B*TD*DE)*sizeof(float);

  hipLaunchKernelGGL(encw_kernel, dim3(512), dim3(256), 0, stream,
                     enc, Wenc, encWT);
  if (use_dwt){
    hipLaunchKernelGGL(decw_kernel, dim3(256), dim3(256), 0, stream,
                       dec, Wdec, decWT);
    hipLaunchKernelGGL((attn_kernel<true>), dim3(512), dim3(512), 0, stream,
                       enc, dec, Wdec, v, encWT, decWT, outCtx, outW);
  } else {
    hipLaunchKernelGGL((attn_kernel<false>), dim3(512), dim3(512), 0, stream,
                       enc, dec, Wdec, v, encWT, decWT, outCtx, outW);
  }
}

// Round 4
// 116.801 us; speedup vs baseline: 1.2993x; 1.1167x over previous
//
#include <hip/hip_runtime.h>

// ContextVector additive-attention (Bahdanau) — round 4.
// Key change: tanh(a+b) = (ta+tb)/(1+ta*tb). Precompute ta=tanh(encW),
// tb=tanh(decW) in prep; phase 1 then needs only 1 rcp/element (was exp+rcp)
// plus packed-f32 VALU (v_pk_*). Prep GEMMs rewritten LDS-free with
// wave-uniform W loads and fused into one kernel.

constexpr int B  = 8;
constexpr int TE = 512;   // T_enc
constexpr int DE = 256;   // D_enc
constexpr int TD = 256;   // T_dec
constexpr int DD = 512;   // D_dec

constexpr float LOG2E  = 1.4426950408889634f;
constexpr float K2     = 2.8853900817779268f;   // 2*log2(e)
constexpr float TCLAMP = 0.99999988f;           // < 1 so 1+ta*tb never hits 0

typedef float f2 __attribute__((ext_vector_type(2)));

__device__ __forceinline__ float fexp2(float x){ return __builtin_amdgcn_exp2f(x); }
__device__ __forceinline__ float frcp (float x){ return __builtin_amdgcn_rcpf(x); }
__device__ __forceinline__ f2 pk_add(f2 a, f2 b){ f2 d; asm("v_pk_add_f32 %0, %1, %2":"=v"(d):"v"(a),"v"(b)); return d; }
__device__ __forceinline__ f2 pk_mul(f2 a, f2 b){ f2 d; asm("v_pk_mul_f32 %0, %1, %2":"=v"(d):"v"(a),"v"(b)); return d; }
__device__ __forceinline__ f2 pk_fma(f2 a, f2 b, f2 c){ f2 d; asm("v_pk_fma_f32 %0, %1, %2, %3":"=v"(d):"v"(a),"v"(b),"v"(c)); return d; }

__device__ __forceinline__ float tanh_fast(float z){
  const float E = fexp2(K2*z);                 // e^{2z}
  const float t = 1.f - 2.f*frcp(1.f + E);
  return fminf(fmaxf(t, -TCLAMP), TCLAMP);
}

// Fused prep: blocks [0,512): encT[b][e][t] = tanh(encW) (transposed store)
//             blocks [512,1024): decT[b*TD+s][e] = tanh(decW) (row-major)
// W reads are wave-uniform (scalar-load friendly); A reads per-lane from L1/L2.
__global__ __launch_bounds__(256)
void prep_kernel(const float* __restrict__ enc, const float* __restrict__ Wenc,
                 const float* __restrict__ dec, const float* __restrict__ Wdec,
                 float* __restrict__ encT, float* __restrict__ decT)
{
  const int tid = threadIdx.x;
  const int bid = blockIdx.x;
  if (bid < 512){
    // encW: 16 row-groups x 32 e-groups (8 cols each)
    const int rg = bid >> 5, eg = bid & 31, e0 = eg*8;
    const int row = rg*256 + tid;          // b*TE + t
    const int b = row >> 9, t = row & (TE-1);
    const float* rp = enc + (size_t)row*DE;
    const float* wp = Wenc + e0;
    float acc[8];
    #pragma unroll
    for (int i=0;i<8;i++) acc[i]=0.f;
    #pragma unroll 2
    for (int k4=0;k4<DE/4;k4++){
      const float4 a = *(const float4*)(rp + 4*k4);
      const float aj[4] = {a.x, a.y, a.z, a.w};
      #pragma unroll
      for (int j=0;j<4;j++){
        const float* wr = wp + (size_t)(4*k4+j)*DE;   // wave-uniform address
        const float4 wa = *(const float4*)wr;
        const float4 wb = *(const float4*)(wr+4);
        acc[0]+=aj[j]*wa.x; acc[1]+=aj[j]*wa.y; acc[2]+=aj[j]*wa.z; acc[3]+=aj[j]*wa.w;
        acc[4]+=aj[j]*wb.x; acc[5]+=aj[j]*wb.y; acc[6]+=aj[j]*wb.z; acc[7]+=aj[j]*wb.w;
      }
    }
    float* op = encT + (size_t)(b*DE + e0)*TE + t;    // coalesced over t
    #pragma unroll
    for (int i=0;i<8;i++) op[(size_t)i*TE] = tanh_fast(acc[i]);
  } else {
    // decW: 8 row-groups x 64 e-groups (4 cols each)
    const int bid2 = bid - 512;
    const int rg = bid2 >> 6, eg = bid2 & 63, e0 = eg*4;
    const int row = rg*256 + tid;          // b*TD + s
    const float* rp = dec + (size_t)row*DD;
    const float* wp = Wdec + e0;
    float acc[4];
    #pragma unroll
    for (int i=0;i<4;i++) acc[i]=0.f;
    #pragma unroll 2
    for (int k4=0;k4<DD/4;k4++){
      const float4 a = *(const float4*)(rp + 4*k4);
      const float aj[4] = {a.x, a.y, a.z, a.w};
      #pragma unroll
      for (int j=0;j<4;j++){
        const float4 w = *(const float4*)(wp + (size_t)(4*k4+j)*DE);  // uniform
        acc[0]+=aj[j]*w.x; acc[1]+=aj[j]*w.y; acc[2]+=aj[j]*w.z; acc[3]+=aj[j]*w.w;
      }
    }
    float* op = decT + (size_t)row*DE + e0;
    #pragma unroll
    for (int i=0;i<4;i++) op[i] = tanh_fast(acc[i]);
  }
}

// Main kernel: block = (b, 4 decoder steps). 512 blocks x 512 threads.
// phase1: acc[s] = sum_e vv'_e * (ta+tb)/(1+ta*tb), vv' = LOG2E*v
// phase2: reduce e-quarter partials + softmax (log2-domain, exp2)
// phase3: context = weights @ enc
template<bool USE_DWT>
__global__ __launch_bounds__(512, 4)
void attn_kernel(const float* __restrict__ enc, const float* __restrict__ dec,
                 const float* __restrict__ Wdec, const float* __restrict__ v,
                 const float* __restrict__ encT, const float* __restrict__ decT,
                 float* __restrict__ outCtx, float* __restrict__ outW)
{
  __shared__ __align__(16) float tw[DE][4];       // 4 KB: tb for 4 s, per e
  __shared__ float vv[DE];                        // 1 KB: LOG2E * v
  __shared__ __align__(16) float part[4][4][TE];  // 32 KB [g][s][t]; reused ph3
  __shared__ __align__(16) float pl[4][TE];       // 8 KB exp values
  __shared__ float wred[8], wsum2[8], rs[4];
  __shared__ __align__(16) float Ds[USE_DWT ? 4 : 4*DD];

  const int tid = threadIdx.x;
  const int b  = blockIdx.x >> 6;
  const int s0 = (blockIdx.x & 63)*4;

  if (USE_DWT){
    if (tid < DE){
      const float* dp = decT + (size_t)(b*TD + s0)*DE + tid;
      float4 t4; t4.x = dp[0]; t4.y = dp[DE]; t4.z = dp[2*DE]; t4.w = dp[3*DE];
      *(float4*)&tw[tid][0] = t4;
      vv[tid] = LOG2E * v[tid];
    }
    __syncthreads();
  } else {
    {
      const float* src = dec + (size_t)(b*TD + s0)*DD;
      float* dsf = (float*)Ds;
      #pragma unroll
      for (int i=0;i<4;i++) dsf[tid + i*512] = src[tid + i*512];
      if (tid < DE) vv[tid] = LOG2E * v[tid];
    }
    __syncthreads();
    const int h = tid >> 8, e = tid & 255;
    float a0=0.f, a1=0.f;
    const float* wp  = Wdec + e;
    const float* d0p = (const float*)Ds + (2*h  )*DD;
    const float* d1p = (const float*)Ds + (2*h+1)*DD;
    #pragma unroll 2
    for (int k4=0;k4<DD/4;k4++){
      const float4 qa = *(const float4*)(d0p + 4*k4);
      const float4 qb = *(const float4*)(d1p + 4*k4);
      const float w0 = wp[(size_t)(4*k4  )*DE];
      const float w1 = wp[(size_t)(4*k4+1)*DE];
      const float w2 = wp[(size_t)(4*k4+2)*DE];
      const float w3 = wp[(size_t)(4*k4+3)*DE];
      a0 += qa.x*w0+qa.y*w1+qa.z*w2+qa.w*w3;
      a1 += qb.x*w0+qb.y*w1+qb.z*w2+qb.w*w3;
    }
    float2 o; o.x = tanh_fast(a0); o.y = tanh_fast(a1);
    *(float2*)&tw[e][2*h] = o;
    __syncthreads();
  }

  // ---- phase 1: energies via tanh addition theorem. thread (g, t-quad q) ----
  {
    const int g = tid >> 7, q = tid & 127;
    f2 acc0[4], acc1[4];
    #pragma unroll
    for (int s=0;s<4;s++){ acc0[s]=(f2)(0.f); acc1[s]=(f2)(0.f); }
    const f2 one = {1.f, 1.f};
    const float* xp = encT + (size_t)(b*DE + 64*g)*TE + 4*q;
    #pragma unroll 2
    for (int i=0;i<64;i++){
      const float4 x = *(const float4*)(xp + (size_t)i*TE);
      const int e = 64*g + i;
      const float4 d = *(const float4*)&tw[e][0];   // uniform b128
      const float ve = vv[e];                       // uniform b32
      const f2 ta01 = {x.x, x.y}, ta23 = {x.z, x.w};
      const f2 ve2  = {ve, ve};
      const float ds_[4] = {d.x, d.y, d.z, d.w};
      #pragma unroll
      for (int s=0;s<4;s++){
        const f2 tb2 = {ds_[s], ds_[s]};
        const f2 u0 = pk_mul(ta01, tb2), u1 = pk_mul(ta23, tb2);
        const f2 n0 = pk_add(ta01, tb2), n1 = pk_add(ta23, tb2);
        const f2 d0 = pk_add(one, u0),   d1 = pk_add(one, u1);
        const f2 r0 = {frcp(d0.x), frcp(d0.y)};
        const f2 r1 = {frcp(d1.x), frcp(d1.y)};
        const f2 q0 = pk_mul(n0, r0), q1 = pk_mul(n1, r1);
        acc0[s] = pk_fma(ve2, q0, acc0[s]);
        acc1[s] = pk_fma(ve2, q1, acc1[s]);
      }
    }
    #pragma unroll
    for (int s=0;s<4;s++){
      float4 st; st.x=acc0[s].x; st.y=acc0[s].y; st.z=acc1[s].x; st.w=acc1[s].y;
      *(float4*)&part[g][s][4*q] = st;
    }
  }
  __syncthreads();

  // ---- phase 2: reduce partials + softmax (log2-domain) ----
  {
    const int w = tid >> 6, lane = tid & 63;
    const int s = w >> 1, c = w & 1;
    const int t0 = c*256 + 4*lane;
    const float4 p0 = *(const float4*)&part[0][s][t0];
    const float4 p1 = *(const float4*)&part[1][s][t0];
    const float4 p2 = *(const float4*)&part[2][s][t0];
    const float4 p3 = *(const float4*)&part[3][s][t0];
    float4 al;
    al.x = p0.x+p1.x+p2.x+p3.x;
    al.y = p0.y+p1.y+p2.y+p3.y;
    al.z = p0.z+p1.z+p2.z+p3.z;
    al.w = p0.w+p1.w+p2.w+p3.w;
    float m = fmaxf(fmaxf(al.x,al.y), fmaxf(al.z,al.w));
    #pragma unroll
    for (int off=32; off>=1; off>>=1) m = fmaxf(m, __shfl_xor(m, off));
    if (lane==0) wred[w] = m;
    __syncthreads();
    const float M = fmaxf(wred[2*s], wred[2*s+1]);
    float4 ex;
    ex.x = fexp2(al.x - M); ex.y = fexp2(al.y - M);
    ex.z = fexp2(al.z - M); ex.w = fexp2(al.w - M);
    float sum = ex.x+ex.y+ex.z+ex.w;
    #pragma unroll
    for (int off=32; off>=1; off>>=1) sum += __shfl_xor(sum, off);
    if (lane==0) wsum2[w] = sum;
    __syncthreads();
    const float S = wsum2[2*s] + wsum2[2*s+1];
    const float r = 1.0f / S;
    float4 wo; wo.x=ex.x*r; wo.y=ex.y*r; wo.z=ex.z*r; wo.w=ex.w*r;
    *(float4*)(outW + (size_t)(b*TD + s0 + s)*TE + t0) = wo;
    *(float4*)&pl[s][t0] = ex;
    if (lane==0 && c==0) rs[s] = r;
  }
  __syncthreads();

  // ---- phase 3: context. thread (h = t-half, e). ----
  {
    const int h = tid >> 8, e = tid & 255;
    float c0=0.f, c1=0.f, c2=0.f, c3=0.f;
    const float* encB = enc + (size_t)(b*TE + 256*h)*DE + e;
    const float* pb = &pl[0][256*h];
    #pragma unroll 2
    for (int t4=0;t4<64;t4++){
      const float4 q0 = *(const float4*)(pb + 0*TE + 4*t4);
      const float4 q1 = *(const float4*)(pb + 1*TE + 4*t4);
      const float4 q2 = *(const float4*)(pb + 2*TE + 4*t4);
      const float4 q3 = *(const float4*)(pb + 3*TE + 4*t4);
      const float f0 = encB[(size_t)(4*t4  )*DE];
      const float f1 = encB[(size_t)(4*t4+1)*DE];
      const float f2_ = encB[(size_t)(4*t4+2)*DE];
      const float f3 = encB[(size_t)(4*t4+3)*DE];
      c0 += q0.x*f0+q0.y*f1+q0.z*f2_+q0.w*f3;
      c1 += q1.x*f0+q1.y*f1+q1.z*f2_+q1.w*f3;
      c2 += q2.x*f0+q2.y*f1+q2.z*f2_+q2.w*f3;
      c3 += q3.x*f0+q3.y*f1+q3.z*f2_+q3.w*f3;
    }
    float* partc = &part[0][0][0];   // reuse as [h][s][e]
    partc[(h*4+0)*DE + e] = c0;
    partc[(h*4+1)*DE + e] = c1;
    partc[(h*4+2)*DE + e] = c2;
    partc[(h*4+3)*DE + e] = c3;
  }
  __syncthreads();
  if (tid < DE){
    const float* partc = &part[0][0][0];
    #pragma unroll
    for (int s=0;s<4;s++){
      const float val = (partc[s*DE + tid] + partc[(4+s)*DE + tid]) * rs[s];
      outCtx[(size_t)(b*TD + s0 + s)*DE + tid] = val;
    }
  }
}

extern "C" void kernel_launch(void* const* d_in, const int* in_sizes, int n_in,
                              void* d_out, int out_size, void* d_ws, size_t ws_size,
                              hipStream_t stream)
{
  const float* enc  = (const float*)d_in[0];
  const float* dec  = (const float*)d_in[1];
  const float* Wenc = (const float*)d_in[2];
  const float* Wdec = (const float*)d_in[3];
  const float* v    = (const float*)d_in[4];
  float* outCtx = (float*)d_out;                       // (8,256,256)
  float* outW   = outCtx + (size_t)B*TD*DE;            // (8,256,512)
  float* encT   = (float*)d_ws;                        // 4 MB
  float* decT   = encT + (size_t)B*DE*TE;              // 2 MB

  const bool use_dwt = ws_size >= (size_t)(B*DE*TE + B*TD*DE)*sizeof(float);

  hipLaunchKernelGGL(prep_kernel, dim3(use_dwt ? 1024 : 512), dim3(256), 0,
                     stream, enc, Wenc, dec, Wdec, encT, decT);
  if (use_dwt){
    hipLaunchKernelGGL((attn_kernel<true>), dim3(512), dim3(512), 0, stream,
                       enc, dec, Wdec, v, encT, decT, outCtx, outW);
  } else {
    hipLaunchKernelGGL((attn_kernel<false>), dim3(512), dim3(512), 0, stream,
                       enc, dec, Wdec, v, encT, decT, outCtx, outW);
  }
}